// Round 6
// baseline (228.039 us; speedup 1.0000x reference)
//
#include <hip/hip_runtime.h>

#define SEQ  3072
#define HID  1280
#define NH   16
#define HD   80
#define NQKV 3840
#define KSP  2

typedef unsigned short u16;
typedef unsigned int u32;
typedef __attribute__((ext_vector_type(8))) short short8;
typedef __attribute__((ext_vector_type(4))) short short4v;
typedef __attribute__((ext_vector_type(4))) float floatx4;
typedef __attribute__((ext_vector_type(4))) unsigned int uint4v;

__device__ __forceinline__ u16 f2bf(float x) {
    u32 u = __float_as_uint(x);
    u += 0x7fffu + ((u >> 16) & 1u);
    return (u16)(u >> 16);
}
__device__ __forceinline__ u32 packrne(float a, float b) {
    return (u32)f2bf(a) | ((u32)f2bf(b) << 16);
}

typedef const __attribute__((address_space(1))) unsigned int* gp1_t;
typedef __attribute__((address_space(3))) unsigned int* lp3_t;
__device__ __forceinline__ void gld16(const void* g, void* l) {
    __builtin_amdgcn_global_load_lds((gp1_t)g, (lp3_t)l, 16, 0, 0);
}

// swizzled 16B-chunk position for 80-dim Q/K rows (10 chunks / 160B):
// main chunks 0..7: ^(r&7); tail 8..9: ^((r>>2)&1)
__device__ __forceinline__ int swz80(int c, int r) {
    return (c < 8) ? (c ^ (r & 7)) : (8 + ((c - 8) ^ ((r >> 2) & 1)));
}

// ---------------- fused prep: rope float2 table | cast hidden | transpose qkv_w | transpose o_w ----------------
__global__ void prep_k(const int* __restrict__ pos, float2* __restrict__ csb,
                       const float* __restrict__ hs,
                       u16* __restrict__ hH, const float* __restrict__ qkvw,
                       u16* __restrict__ wT, const float* __restrict__ ow,
                       u16* __restrict__ owT) {
    __shared__ float tile[32][33];
    const int b = blockIdx.x, t = threadIdx.x;
    if (b < 480) {  // rope table: 3072 x 40 of (cos,sin)
        int i = b * 256 + t;
        int s = i / 40, j = i % 40;
        float p = (float)((j < 20) ? pos[s * 2] : pos[s * 2 + 1]);
        int k = (j < 20) ? j : j - 20;
        float inv = powf(10000.0f, -(float)k / 20.0f);
        float a = p * inv;
        csb[s * 40 + j] = make_float2(cosf(a), sinf(a));
    } else if (b < 4320) {  // cast hidden f32 -> bf16, vec4
        int i = (b - 480) * 256 + t;  // < 983040
        const float4 x = ((const float4*)hs)[i];
        uint2 o;
        o.x = packrne(x.x, x.y);
        o.y = packrne(x.z, x.w);
        ((uint2*)hH)[i] = o;
    } else {
        const float* w;
        u16* dst;
        int K, N, nx, ky;
        if (b < 9120) {
            int i = b - 4320;
            nx = i % 120; ky = i / 120; w = qkvw; dst = wT; K = HID; N = NQKV;
        } else {
            int i = b - 9120;
            nx = i % 40; ky = i / 40; w = ow; dst = owT; K = HID; N = HID;
        }
        int n0 = nx * 32, k0 = ky * 32;
        int c = t & 31, r8 = t >> 5;
        for (int rr = r8; rr < 32; rr += 8)
            tile[rr][c] = w[(size_t)(k0 + rr) * N + n0 + c];
        __syncthreads();
        for (int rr = r8; rr < 32; rr += 8)
            dst[(size_t)(n0 + rr) * K + k0 + c] = f2bf(tile[c][rr]);
    }
}

// ---------------- fused QKV GEMM: 128m x 80n (one head) per block, rope+pack epilogue ----------------
__global__ __launch_bounds__(256, 4) void gemm_qkv_k(
    const u16* __restrict__ A, const u16* __restrict__ B,
    const float* __restrict__ bias, const float2* __restrict__ csb,
    u16* __restrict__ Qs, u16* __restrict__ Ks, u16* __restrict__ Vs) {
    __shared__ u16 lA[128 * 64], lB[80 * 64];
    const int t = threadIdx.x, lane = t & 63, w = t >> 6;
    const int qi = lane & 15, quad = lane >> 4;
    const int K = HID;
    int id = blockIdx.x;
    int xcd = id & 7, sN = id >> 3;                 // 1152 = 8 * 144
    int m_idx = (xcd >> 1) * 6 + sN / 24;           // 0..23
    int n_idx = (xcd & 1) * 24 + sN % 24;           // 0..47
    const int m0 = m_idx * 128;
    const int nb = n_idx * 80;

    floatx4 acc[2][5];
    for (int mi = 0; mi < 2; mi++)
        for (int ni = 0; ni < 5; ni++) acc[mi][ni] = (floatx4){0.f, 0.f, 0.f, 0.f};

    const int rg = lane >> 3;
    const int ce = ((lane & 7) ^ rg) * 8;
    size_t gA[4];
    for (int j = 0; j < 4; j++) {
        int row = m0 + (w * 4 + j) * 8 + rg;
        gA[j] = (size_t)row * K + ce;
    }
    size_t gB[3];
    int nB = 0;
    for (int g = w; g < 10; g += 4) {
        int row = nb + g * 8 + rg;
        gB[nB++] = (size_t)row * K + ce;
    }

    for (int k0 = 0; k0 < K; k0 += 64) {
        for (int j = 0; j < 4; j++)
            gld16(A + gA[j] + k0, &lA[((w * 4 + j) * 8) * 64]);
        {
            int bi = 0;
            for (int g = w; g < 10; g += 4)
                gld16(B + gB[bi++] + k0, &lB[(g * 8) * 64]);
        }
        __syncthreads();
        short8 af[2][2];
        for (int mi = 0; mi < 2; mi++) {
            int row = w * 32 + mi * 16 + qi;
            for (int kh = 0; kh < 2; kh++)
                af[mi][kh] = *(const short8*)&lA[row * 64 + (((kh * 4 + quad) ^ (row & 7)) << 3)];
        }
#pragma unroll
        for (int ni = 0; ni < 5; ni++) {
            int row = ni * 16 + qi;
            short8 b0 = *(const short8*)&lB[row * 64 + ((quad ^ (row & 7)) << 3)];
            short8 b1 = *(const short8*)&lB[row * 64 + (((4 + quad) ^ (row & 7)) << 3)];
            for (int mi = 0; mi < 2; mi++) {
                acc[mi][ni] = __builtin_amdgcn_mfma_f32_16x16x32_bf16(af[mi][0], b0, acc[mi][ni], 0, 0, 0);
                acc[mi][ni] = __builtin_amdgcn_mfma_f32_16x16x32_bf16(af[mi][1], b1, acc[mi][ni], 0, 0, 0);
            }
        }
        __syncthreads();
    }

    const int ht = n_idx >> 4;   // 0=Q, 1=K, 2=V
    const int h = n_idx & 15;
    float bs[5];
    for (int ni = 0; ni < 5; ni++)
        bs[ni] = bias[ht * HID + h * HD + ni * 16 + qi];

    if (ht == 2) {
        // V: transpose to Vs[(h*80+d)*SEQ + ...] with pc swizzle
        for (int mi = 0; mi < 2; mi++) {
            int s = m0 + w * 32 + mi * 16 + quad * 4;
            int g = (s & 63) >> 2;
            size_t base = (size_t)(s & ~63);
            for (int ni = 0; ni < 5; ni++) {
                int d = ni * 16 + qi;
                uint2 o;
                o.x = packrne(acc[mi][ni][0] + bs[ni], acc[mi][ni][1] + bs[ni]);
                o.y = packrne(acc[mi][ni][2] + bs[ni], acc[mi][ni][3] + bs[ni]);
                int pc = (g >> 1) ^ (d & 7);
                *(uint2*)&Vs[((size_t)h * HD + d) * SEQ + base + pc * 8 + (g & 1) * 4] = o;
            }
        }
    } else {
        const float qsc = (ht == 0) ? 0.11180339887498949f * 1.4426950408889634f : 1.0f;
        u16* dst = (ht == 0) ? Qs : Ks;
        int dm[5];
        dm[0] = qi;
        dm[1] = 16 + qi;
        dm[2] = (qi & 8) ? (qi - 8) : (32 + qi);
        dm[3] = 8 + qi;
        dm[4] = 24 + qi;
        for (int mi = 0; mi < 2; mi++) {
#pragma unroll
            for (int r = 0; r < 4; r++) {
                int s = m0 + w * 32 + mi * 16 + quad * 4 + r;
                float val[5], sh[5];
                for (int ni = 0; ni < 5; ni++) val[ni] = acc[mi][ni][r] + bs[ni];
                for (int ni = 0; ni < 5; ni++) sh[ni] = __shfl_xor(val[ni], 8);
                const float2* cr = csb + (size_t)s * 40;
                float out[5];
                {
                    float2 c0 = cr[dm[0]];
                    float p = (qi & 8) ? sh[3] : sh[2];
                    out[0] = (val[0] * c0.x - p * c0.y) * qsc;
                    float2 c1 = cr[dm[1]];
                    p = (qi & 8) ? sh[4] : sh[3];
                    out[1] = (val[1] * c1.x - p * c1.y) * qsc;
                    float2 c2 = cr[dm[2]];
                    if (qi & 8) out[2] = (val[2] * c2.x + sh[0] * c2.y) * qsc;
                    else        out[2] = (val[2] * c2.x - sh[4] * c2.y) * qsc;
                    float2 c3 = cr[dm[3]];
                    p = (qi & 8) ? sh[1] : sh[0];
                    out[3] = (val[3] * c3.x + p * c3.y) * qsc;
                    float2 c4 = cr[dm[4]];
                    p = (qi & 8) ? sh[2] : sh[1];
                    out[4] = (val[4] * c4.x + p * c4.y) * qsc;
                }
                size_t rowb = (size_t)(h * SEQ + s) * 80;
                for (int ni = 0; ni < 5; ni++) {
                    int c = 2 * ni + (qi >> 3);
                    dst[rowb + swz80(c, s) * 8 + (qi & 7)] = f2bf(out[ni]);
                }
            }
        }
    }
}

// ---------------- bf16 GEMM (O-proj): C[M][N] = A[M][K] * Bt[N][K]^T + bias ----------------
template<int BM, int BN>
__global__ __launch_bounds__(256, 3) void gemm_bf16_k(
    const u16* __restrict__ A, const u16* __restrict__ B,
    const float* __restrict__ bias, float* __restrict__ C,
    int M, int N, int K, int mode) {
    constexpr int GA = BM / 32;
    constexpr int GB = BN / 32;
    constexpr int FM = BM / 32;
    constexpr int FN = BN / 32;
    __shared__ u16 lA[BM * 64], lB[BN * 64];
    const int t = threadIdx.x, lane = t & 63, w = t >> 6;
    const int qi = lane & 15, quad = lane >> 4;
    int id = blockIdx.x;
    int xcd = id & 7, sN = id >> 3;
    int m_idx, n_idx;
    if (mode == 0) {
        n_idx = (xcd & 1) * 15 + sN % 15;
        m_idx = (xcd >> 1) * 6 + sN / 15;
    } else {          // O-proj 64x64: 20n x 48m tiles, 6m x 20n patch per XCD
        m_idx = xcd * 6 + sN / 20;
        n_idx = sN % 20;
    }
    const int m0 = m_idx * BM, n0 = n_idx * BN;
    const int wm = (w >> 1) * (BM / 2), wn = (w & 1) * (BN / 2);

    floatx4 acc[FM][FN];
    for (int mi = 0; mi < FM; mi++)
        for (int ni = 0; ni < FN; ni++) acc[mi][ni] = (floatx4){0.f, 0.f, 0.f, 0.f};

    const int rg = lane >> 3;
    const int ce = ((lane & 7) ^ rg) * 8;
    size_t gA[GA], gB[GB];
    for (int g = 0; g < GA; g++) {
        int row = w * (BM / 4) + g * 8 + rg;
        gA[g] = (size_t)(m0 + row) * K + ce;
    }
    for (int g = 0; g < GB; g++) {
        int row = w * (BN / 4) + g * 8 + rg;
        gB[g] = (size_t)(n0 + row) * K + ce;
    }

    for (int k0 = 0; k0 < K; k0 += 64) {
        for (int g = 0; g < GA; g++)
            gld16(A + gA[g] + k0, &lA[(w * (BM / 4) + g * 8) * 64]);
        for (int g = 0; g < GB; g++)
            gld16(B + gB[g] + k0, &lB[(w * (BN / 4) + g * 8) * 64]);
        __syncthreads();
        short8 af[FM][2], bf[FN][2];
        for (int mi = 0; mi < FM; mi++) {
            int row = wm + mi * 16 + qi;
            for (int kh = 0; kh < 2; kh++)
                af[mi][kh] = *(const short8*)&lA[row * 64 + (((kh * 4 + quad) ^ (row & 7)) << 3)];
        }
        for (int ni = 0; ni < FN; ni++) {
            int row = wn + ni * 16 + qi;
            for (int kh = 0; kh < 2; kh++)
                bf[ni][kh] = *(const short8*)&lB[row * 64 + (((kh * 4 + quad) ^ (row & 7)) << 3)];
        }
        for (int mi = 0; mi < FM; mi++)
            for (int ni = 0; ni < FN; ni++) {
                acc[mi][ni] = __builtin_amdgcn_mfma_f32_16x16x32_bf16(af[mi][0], bf[ni][0], acc[mi][ni], 0, 0, 0);
                acc[mi][ni] = __builtin_amdgcn_mfma_f32_16x16x32_bf16(af[mi][1], bf[ni][1], acc[mi][ni], 0, 0, 0);
            }
        __syncthreads();
    }
    for (int mi = 0; mi < FM; mi++)
        for (int ni = 0; ni < FN; ni++) {
            int col = n0 + wn + ni * 16 + qi;
            int rowb = m0 + wm + mi * 16 + quad * 4;
            float b = bias[col];
            for (int r = 0; r < 4; r++)
                C[(size_t)(rowb + r) * N + col] = acc[mi][ni][r] + b;
        }
}

// ---------------- flash attention: QT=128, 4 waves x 32q (2 qg), key-split 2 ----------------
// Counted-vmcnt dual-barrier pipeline (T3/T4 minimum 2-phase): each wave issues exactly
// 5 gld16 per stage; the pre-compute wait is vmcnt(5) so stage(it+1)'s 5 loads stay in
// flight across the whole compute phase (no drain-0). Second barrier protects buf reuse.
__global__ __launch_bounds__(256, 3) void attn_k(
    const u16* __restrict__ Qs, const u16* __restrict__ Ks, const u16* __restrict__ Vs,
    float* __restrict__ Op, float* __restrict__ lp) {
    __shared__ u16 kbuf[2][5120];  // 10KB each; pair doubles as 20KB Q staging
    __shared__ u16 vbuf[2][5120];  // 10KB each

    const int t = threadIdx.x, lane = t & 63, w = t >> 6;  // w in 0..3
    const int qi = lane & 15, quad = lane >> 4;
    const int h = blockIdx.y, q0 = blockIdx.x * 128, ksp = blockIdx.z;
    const int kc0 = ksp * (SEQ / 2);
    u16* const kflat = &kbuf[0][0];

    {   // stage Q: 128 rows x 160B = 20KB across the kbuf pair
        const u16* Qt = Qs + (size_t)(h * SEQ + q0) * 80;
        for (int j = 0; j < 5; j++) {
            int o = (w * 5 + j) * 512;
            gld16(Qt + o + lane * 8, kflat + o);
        }
    }
    __syncthreads();
    short8 bq[2][3];
    for (int qg = 0; qg < 2; qg++) {
        const u16* rb = &kflat[(w * 32 + qg * 16 + qi) * 80];
        bq[qg][0] = *(const short8*)&rb[(quad ^ (qi & 7)) << 3];
        bq[qg][1] = *(const short8*)&rb[((4 + quad) ^ (qi & 7)) << 3];
        short4v t2 = *(const short4v*)&rb[((8 + ((quad >> 1) ^ ((qi >> 2) & 1))) << 3) + ((quad & 1) << 2)];
        bq[qg][2] = (short8){t2.x, t2.y, t2.z, t2.w, 0, 0, 0, 0};
    }
    __syncthreads();   // all waves done reading Q area before stage(0) overwrites it

    float l_lane[2] = {0.f, 0.f};
    floatx4 acco[2][5];
    for (int qg = 0; qg < 2; qg++)
        for (int dt = 0; dt < 5; dt++) acco[qg][dt] = (floatx4){0.f, 0.f, 0.f, 0.f};

    const u16* const Kt = Ks + (size_t)(h * SEQ + kc0) * 80;
    const u16* const Vt = Vs + (size_t)h * HD * SEQ + kc0;
    // uniform staging: 20 16B-chunk groups (10 K + 10 V), exactly 5 gld16 per wave
    auto stage = [&](int it, int buf) {
        const u16* Kti = Kt + it * (64 * 80);
        const u16* Vti = Vt + it * 64;
        for (int c = 0; c < 5; c++) {
            int j = w * 5 + c;
            if (j < 10) {
                gld16(Kti + j * 512 + lane * 8, &kbuf[buf][j * 512]);
            } else {
                int i = j - 10;
                int p16 = i * 64 + lane;
                int d = p16 >> 3, pc = p16 & 7;
                gld16(Vti + (size_t)d * SEQ + pc * 8, &vbuf[buf][i * 512]);
            }
        }
    };
    stage(0, 0);

    const int NT = (SEQ / 2) / 64;  // 24
    for (int it = 0; it < NT; it++) {
        int cur = it & 1;
        if (it + 1 < NT) {
            stage(it + 1, cur ^ 1);
            // wait only for stage(it): the 5 newest (stage(it+1)) stay in flight
            asm volatile("s_waitcnt vmcnt(5)" ::: "memory");
        } else {
            asm volatile("s_waitcnt vmcnt(0)" ::: "memory");
        }
        __builtin_amdgcn_s_barrier();
        __builtin_amdgcn_sched_barrier(0);
        const u16* kb = &kbuf[cur][0];
        const u16* vb = &vbuf[cur][0];
#pragma unroll
        for (int c2 = 0; c2 < 2; c2++) {
            u32 pkx[2][2], pky[2][2];  // [qg][ktl]
#pragma unroll
            for (int ktl = 0; ktl < 2; ktl++) {
                int arow = (c2 * 2 + ktl) * 16 + qi;
                const u16* rb = &kb[arow * 80];
                short8 a0 = *(const short8*)&rb[(quad ^ (qi & 7)) << 3];
                short8 a1 = *(const short8*)&rb[((4 + quad) ^ (qi & 7)) << 3];
                short4v a2v = *(const short4v*)&rb[((8 + ((quad >> 1) ^ ((qi >> 2) & 1))) << 3) + ((quad & 1) << 2)];
                short8 a2 = (short8){a2v.x, a2v.y, a2v.z, a2v.w, 0, 0, 0, 0};
#pragma unroll
                for (int qg = 0; qg < 2; qg++) {
                    floatx4 s = (floatx4){0.f, 0.f, 0.f, 0.f};
                    __builtin_amdgcn_s_setprio(1);
                    s = __builtin_amdgcn_mfma_f32_16x16x32_bf16(a0, bq[qg][0], s, 0, 0, 0);
                    s = __builtin_amdgcn_mfma_f32_16x16x32_bf16(a1, bq[qg][1], s, 0, 0, 0);
                    s = __builtin_amdgcn_mfma_f32_16x16x32_bf16(a2, bq[qg][2], s, 0, 0, 0);
                    __builtin_amdgcn_s_setprio(0);
                    float e0 = __builtin_amdgcn_exp2f(s[0]);
                    float e1 = __builtin_amdgcn_exp2f(s[1]);
                    float e2 = __builtin_amdgcn_exp2f(s[2]);
                    float e3 = __builtin_amdgcn_exp2f(s[3]);
                    l_lane[qg] += (e0 + e1) + (e2 + e3);
                    pkx[qg][ktl] = __builtin_amdgcn_perm(__float_as_uint(e1), __float_as_uint(e0), 0x07060302u);
                    pky[qg][ktl] = __builtin_amdgcn_perm(__float_as_uint(e3), __float_as_uint(e2), 0x07060302u);
                }
            }
            short8 bp[2];
#pragma unroll
            for (int qg = 0; qg < 2; qg++) {
                auto s0 = __builtin_amdgcn_permlane32_swap(pkx[qg][0], pkx[qg][1], false, false);
                auto s1 = __builtin_amdgcn_permlane32_swap(pky[qg][0], pky[qg][1], false, false);
                auto t0 = __builtin_amdgcn_permlane16_swap(s0[0], s0[1], false, false);
                auto t1 = __builtin_amdgcn_permlane16_swap(s1[0], s1[1], false, false);
                uint4v bb = (uint4v){t0[0], t1[0], t0[1], t1[1]};
                bp[qg] = __builtin_bit_cast(short8, bb);
            }
            int pv = (4 * c2 + quad) ^ (qi & 7);
            __builtin_amdgcn_s_setprio(1);
#pragma unroll
            for (int dt = 0; dt < 5; dt++) {
                short8 av = *(const short8*)&vb[((dt * 16 + qi) * 8 + pv) * 8];
                acco[0][dt] = __builtin_amdgcn_mfma_f32_16x16x32_bf16(av, bp[0], acco[0][dt], 0, 0, 0);
                acco[1][dt] = __builtin_amdgcn_mfma_f32_16x16x32_bf16(av, bp[1], acco[1][dt], 0, 0, 0);
            }
            __builtin_amdgcn_s_setprio(0);
        }
        // all waves done reading buf[cur] before next iter's stage overwrites it
        __builtin_amdgcn_s_barrier();
    }

    for (int qg = 0; qg < 2; qg++) {
        float lq = l_lane[qg];
        lq += __shfl_xor(lq, 16);
        lq += __shfl_xor(lq, 32);
        int q = q0 + w * 32 + qg * 16 + qi;
        if (quad == 0) lp[(size_t)(ksp * NH + h) * SEQ + q] = lq;
        for (int dt = 0; dt < 5; dt++)
            for (int r = 0; r < 4; r++) {
                int d = dt * 16 + quad * 4 + r;
                Op[((size_t)(ksp * NH + h) * HD + d) * SEQ + q] = acco[qg][dt][r];
            }
    }
}

// ---------------- merge key-split partials -> att bf16 [SEQ][HID] ----------------
__global__ void merge_k(const float* __restrict__ Op, const float* __restrict__ lp,
                        u16* __restrict__ att) {
    __shared__ float ls[HD * 65];
    __shared__ float li[64];
    const int t = threadIdx.x;
    const int h = blockIdx.y, q0 = blockIdx.x * 64;
    for (int i = t; i < HD * 16; i += 256) {
        int d = i / 16, g = i % 16;
        size_t a0 = ((size_t)h * HD + d) * SEQ + q0 + g * 4;
        size_t a1 = ((size_t)(NH + h) * HD + d) * SEQ + q0 + g * 4;
        const float4 v0 = *(const float4*)&Op[a0];
        const float4 v1 = *(const float4*)&Op[a1];
        ls[d * 65 + g * 4 + 0] = v0.x + v1.x;
        ls[d * 65 + g * 4 + 1] = v0.y + v1.y;
        ls[d * 65 + g * 4 + 2] = v0.z + v1.z;
        ls[d * 65 + g * 4 + 3] = v0.w + v1.w;
    }
    if (t < 64)
        li[t] = 1.0f / (lp[(size_t)h * SEQ + q0 + t] + lp[(size_t)(NH + h) * SEQ + q0 + t]);
    __syncthreads();
    for (int i = t; i < 64 * 40; i += 256) {
        int ql = i / 40, dg = i % 40;
        int d0 = dg * 2;
        float s = li[ql];
        u32 o = packrne(ls[d0 * 65 + ql] * s, ls[(d0 + 1) * 65 + ql] * s);
        *(u32*)&att[(size_t)(q0 + ql) * HID + h * HD + d0] = o;
    }
}

extern "C" void kernel_launch(void* const* d_in, const int* in_sizes, int n_in,
                              void* d_out, int out_size, void* d_ws, size_t ws_size,
                              hipStream_t stream) {
    const float* hs   = (const float*)d_in[0];
    const int*   pos  = (const int*)d_in[1];
    const float* qkvw = (const float*)d_in[2];
    const float* qkvb = (const float*)d_in[3];
    const float* ow   = (const float*)d_in[4];
    const float* ob   = (const float*)d_in[5];
    float* out = (float*)d_out;

    char* p = (char*)d_ws;
    auto alloc = [&](size_t bytes) {
        char* r = p;
        p += (bytes + 255) & ~(size_t)255;
        return r;
    };
    float2* csb = (float2*)alloc((size_t)SEQ * 40 * 8);          // rope (cos,sin) table
    u16* owT = (u16*)alloc((size_t)HID * HID * 2);
    u16* hH  = (u16*)alloc((size_t)SEQ * HID * 2);               // phase A; aliased by att later
    u16* Qs  = (u16*)alloc((size_t)NH * SEQ * HD * 2);
    u16* Ks  = (u16*)alloc((size_t)NH * SEQ * HD * 2);
    u16* Vs  = (u16*)alloc((size_t)NH * SEQ * HD * 2);
    // pool: phase A = qkv_w^T bf16 (9.8MB); phase B = Op f32 partials (31.5MB)
    char* poolB = alloc((size_t)KSP * NH * HD * SEQ * 4);
    u16* wT = (u16*)poolB;
    float* Op = (float*)poolB;
    float* lp = (float*)alloc((size_t)KSP * NH * SEQ * 4);
    u16* att = hH;  // alias: hH dead after qkv GEMM; att born in merge

    hipLaunchKernelGGL(prep_k, dim3(10720), dim3(256), 0, stream,
                       pos, csb, hs, hH, qkvw, wT, ow, owT);
    hipLaunchKernelGGL(gemm_qkv_k, dim3(1152), dim3(256), 0, stream,
                       hH, wT, qkvb, csb, Qs, Ks, Vs);
    hipLaunchKernelGGL(attn_k, dim3(SEQ / 128, NH, 2), dim3(256), 0, stream,
                       Qs, Ks, Vs, Op, lp);
    hipLaunchKernelGGL(merge_k, dim3(SEQ / 64, NH), dim3(256), 0, stream, Op, lp, att);
    hipLaunchKernelGGL((gemm_bf16_k<64, 64>), dim3(960), dim3(256), 0, stream,
                       att, owT, ob, out, SEQ, HID, HID, 1);
}

// Round 7
// 215.197 us; speedup vs baseline: 1.0597x; 1.0597x over previous
//
#include <hip/hip_runtime.h>

#define SEQ  3072
#define HID  1280
#define NH   16
#define HD   80
#define NQKV 3840
#define KSP  2

typedef unsigned short u16;
typedef unsigned int u32;
typedef __attribute__((ext_vector_type(8))) short short8;
typedef __attribute__((ext_vector_type(4))) short short4v;
typedef __attribute__((ext_vector_type(4))) float floatx4;
typedef __attribute__((ext_vector_type(4))) unsigned int uint4v;

__device__ __forceinline__ u16 f2bf(float x) {
    u32 u = __float_as_uint(x);
    u += 0x7fffu + ((u >> 16) & 1u);
    return (u16)(u >> 16);
}
__device__ __forceinline__ u32 packrne(float a, float b) {
    return (u32)f2bf(a) | ((u32)f2bf(b) << 16);
}

typedef const __attribute__((address_space(1))) unsigned int* gp1_t;
typedef __attribute__((address_space(3))) unsigned int* lp3_t;
__device__ __forceinline__ void gld16(const void* g, void* l) {
    __builtin_amdgcn_global_load_lds((gp1_t)g, (lp3_t)l, 16, 0, 0);
}

// swizzled 16B-chunk position for 80-dim Q/K rows (10 chunks / 160B):
// main chunks 0..7: ^(r&7); tail 8..9: ^((r>>2)&1)
__device__ __forceinline__ int swz80(int c, int r) {
    return (c < 8) ? (c ^ (r & 7)) : (8 + ((c - 8) ^ ((r >> 2) & 1)));
}

// ---------------- fused prep: rope float2 table | cast hidden | transpose qkv_w | transpose o_w ----------------
__global__ void prep_k(const int* __restrict__ pos, float2* __restrict__ csb,
                       const float* __restrict__ hs,
                       u16* __restrict__ hH, const float* __restrict__ qkvw,
                       u16* __restrict__ wT, const float* __restrict__ ow,
                       u16* __restrict__ owT) {
    __shared__ float tile[32][33];
    const int b = blockIdx.x, t = threadIdx.x;
    if (b < 480) {  // rope table: 3072 x 40 of (cos,sin)
        int i = b * 256 + t;
        int s = i / 40, j = i % 40;
        float p = (float)((j < 20) ? pos[s * 2] : pos[s * 2 + 1]);
        int k = (j < 20) ? j : j - 20;
        float inv = powf(10000.0f, -(float)k / 20.0f);
        float a = p * inv;
        csb[s * 40 + j] = make_float2(cosf(a), sinf(a));
    } else if (b < 4320) {  // cast hidden f32 -> bf16, vec4
        int i = (b - 480) * 256 + t;  // < 983040
        const float4 x = ((const float4*)hs)[i];
        uint2 o;
        o.x = packrne(x.x, x.y);
        o.y = packrne(x.z, x.w);
        ((uint2*)hH)[i] = o;
    } else {
        const float* w;
        u16* dst;
        int K, N, nx, ky;
        if (b < 9120) {
            int i = b - 4320;
            nx = i % 120; ky = i / 120; w = qkvw; dst = wT; K = HID; N = NQKV;
        } else {
            int i = b - 9120;
            nx = i % 40; ky = i / 40; w = ow; dst = owT; K = HID; N = HID;
        }
        int n0 = nx * 32, k0 = ky * 32;
        int c = t & 31, r8 = t >> 5;
        for (int rr = r8; rr < 32; rr += 8)
            tile[rr][c] = w[(size_t)(k0 + rr) * N + n0 + c];
        __syncthreads();
        for (int rr = r8; rr < 32; rr += 8)
            dst[(size_t)(n0 + rr) * K + k0 + c] = f2bf(tile[c][rr]);
    }
}

// ---------------- fused QKV GEMM: 192m x 80n (one head) per block, rope+pack epilogue ----------------
// BM=192: each wave owns 48 rows (3 mi x 5 ni = 30 MFMA vs 16 ds_read per K-step,
// MFMA:LDS 1.875 vs 1.43 at BM=128). Grid 16m x 48n = 768 blocks = exactly 3/CU.
// Epilogue (rope via shfl_xor(8) + swizzled pack) is row-parameterized: only the
// row formula changes vs the round-3-verified version.
__global__ __launch_bounds__(256, 3) void gemm_qkv_k(
    const u16* __restrict__ A, const u16* __restrict__ B,
    const float* __restrict__ bias, const float2* __restrict__ csb,
    u16* __restrict__ Qs, u16* __restrict__ Ks, u16* __restrict__ Vs) {
    __shared__ u16 lA[192 * 64], lB[80 * 64];
    const int t = threadIdx.x, lane = t & 63, w = t >> 6;
    const int qi = lane & 15, quad = lane >> 4;
    const int K = HID;
    int id = blockIdx.x;
    int xcd = id & 7, sN = id >> 3;                 // 768 = 8 * 96
    int m_idx = (xcd >> 1) * 4 + sN / 24;           // 0..15
    int n_idx = (xcd & 1) * 24 + sN % 24;           // 0..47
    const int m0 = m_idx * 192;
    const int nb = n_idx * 80;

    floatx4 acc[3][5];
    for (int mi = 0; mi < 3; mi++)
        for (int ni = 0; ni < 5; ni++) acc[mi][ni] = (floatx4){0.f, 0.f, 0.f, 0.f};

    const int rg = lane >> 3;
    const int ce = ((lane & 7) ^ rg) * 8;
    size_t gA[6];
    for (int j = 0; j < 6; j++) {
        int row = m0 + (w * 6 + j) * 8 + rg;
        gA[j] = (size_t)row * K + ce;
    }
    size_t gB[3];
    int nB = 0;
    for (int g = w; g < 10; g += 4) {
        int row = nb + g * 8 + rg;
        gB[nB++] = (size_t)row * K + ce;
    }

    for (int k0 = 0; k0 < K; k0 += 64) {
        for (int j = 0; j < 6; j++)
            gld16(A + gA[j] + k0, &lA[((w * 6 + j) * 8) * 64]);
        {
            int bi = 0;
            for (int g = w; g < 10; g += 4)
                gld16(B + gB[bi++] + k0, &lB[(g * 8) * 64]);
        }
        __syncthreads();
        short8 af[3][2];
        for (int mi = 0; mi < 3; mi++) {
            int row = w * 48 + mi * 16 + qi;
            for (int kh = 0; kh < 2; kh++)
                af[mi][kh] = *(const short8*)&lA[row * 64 + (((kh * 4 + quad) ^ (row & 7)) << 3)];
        }
#pragma unroll
        for (int ni = 0; ni < 5; ni++) {
            int row = ni * 16 + qi;
            short8 b0 = *(const short8*)&lB[row * 64 + ((quad ^ (row & 7)) << 3)];
            short8 b1 = *(const short8*)&lB[row * 64 + (((4 + quad) ^ (row & 7)) << 3)];
            for (int mi = 0; mi < 3; mi++) {
                acc[mi][ni] = __builtin_amdgcn_mfma_f32_16x16x32_bf16(af[mi][0], b0, acc[mi][ni], 0, 0, 0);
                acc[mi][ni] = __builtin_amdgcn_mfma_f32_16x16x32_bf16(af[mi][1], b1, acc[mi][ni], 0, 0, 0);
            }
        }
        __syncthreads();
    }

    const int ht = n_idx >> 4;   // 0=Q, 1=K, 2=V
    const int h = n_idx & 15;
    float bs[5];
    for (int ni = 0; ni < 5; ni++)
        bs[ni] = bias[ht * HID + h * HD + ni * 16 + qi];

    if (ht == 2) {
        // V: transpose to Vs[(h*80+d)*SEQ + ...] with pc swizzle
        for (int mi = 0; mi < 3; mi++) {
            int s = m0 + w * 48 + mi * 16 + quad * 4;
            int g = (s & 63) >> 2;
            size_t base = (size_t)(s & ~63);
            for (int ni = 0; ni < 5; ni++) {
                int d = ni * 16 + qi;
                uint2 o;
                o.x = packrne(acc[mi][ni][0] + bs[ni], acc[mi][ni][1] + bs[ni]);
                o.y = packrne(acc[mi][ni][2] + bs[ni], acc[mi][ni][3] + bs[ni]);
                int pc = (g >> 1) ^ (d & 7);
                *(uint2*)&Vs[((size_t)h * HD + d) * SEQ + base + pc * 8 + (g & 1) * 4] = o;
            }
        }
    } else {
        const float qsc = (ht == 0) ? 0.11180339887498949f * 1.4426950408889634f : 1.0f;
        u16* dst = (ht == 0) ? Qs : Ks;
        int dm[5];
        dm[0] = qi;
        dm[1] = 16 + qi;
        dm[2] = (qi & 8) ? (qi - 8) : (32 + qi);
        dm[3] = 8 + qi;
        dm[4] = 24 + qi;
        for (int mi = 0; mi < 3; mi++) {
#pragma unroll
            for (int r = 0; r < 4; r++) {
                int s = m0 + w * 48 + mi * 16 + quad * 4 + r;
                float val[5], sh[5];
                for (int ni = 0; ni < 5; ni++) val[ni] = acc[mi][ni][r] + bs[ni];
                for (int ni = 0; ni < 5; ni++) sh[ni] = __shfl_xor(val[ni], 8);
                const float2* cr = csb + (size_t)s * 40;
                float out[5];
                {
                    float2 c0 = cr[dm[0]];
                    float p = (qi & 8) ? sh[3] : sh[2];
                    out[0] = (val[0] * c0.x - p * c0.y) * qsc;
                    float2 c1 = cr[dm[1]];
                    p = (qi & 8) ? sh[4] : sh[3];
                    out[1] = (val[1] * c1.x - p * c1.y) * qsc;
                    float2 c2 = cr[dm[2]];
                    if (qi & 8) out[2] = (val[2] * c2.x + sh[0] * c2.y) * qsc;
                    else        out[2] = (val[2] * c2.x - sh[4] * c2.y) * qsc;
                    float2 c3 = cr[dm[3]];
                    p = (qi & 8) ? sh[1] : sh[0];
                    out[3] = (val[3] * c3.x + p * c3.y) * qsc;
                    float2 c4 = cr[dm[4]];
                    p = (qi & 8) ? sh[2] : sh[1];
                    out[4] = (val[4] * c4.x + p * c4.y) * qsc;
                }
                size_t rowb = (size_t)(h * SEQ + s) * 80;
                for (int ni = 0; ni < 5; ni++) {
                    int c = 2 * ni + (qi >> 3);
                    dst[rowb + swz80(c, s) * 8 + (qi & 7)] = f2bf(out[ni]);
                }
            }
        }
    }
}

// ---------------- bf16 GEMM (O-proj): C[M][N] = A[M][K] * Bt[N][K]^T + bias ----------------
template<int BM, int BN>
__global__ __launch_bounds__(256, 3) void gemm_bf16_k(
    const u16* __restrict__ A, const u16* __restrict__ B,
    const float* __restrict__ bias, float* __restrict__ C,
    int M, int N, int K, int mode) {
    constexpr int GA = BM / 32;
    constexpr int GB = BN / 32;
    constexpr int FM = BM / 32;
    constexpr int FN = BN / 32;
    __shared__ u16 lA[BM * 64], lB[BN * 64];
    const int t = threadIdx.x, lane = t & 63, w = t >> 6;
    const int qi = lane & 15, quad = lane >> 4;
    int id = blockIdx.x;
    int xcd = id & 7, sN = id >> 3;
    int m_idx, n_idx;
    if (mode == 0) {
        n_idx = (xcd & 1) * 15 + sN % 15;
        m_idx = (xcd >> 1) * 6 + sN / 15;
    } else {          // O-proj 64x64: 20n x 48m tiles, 6m x 20n patch per XCD
        m_idx = xcd * 6 + sN / 20;
        n_idx = sN % 20;
    }
    const int m0 = m_idx * BM, n0 = n_idx * BN;
    const int wm = (w >> 1) * (BM / 2), wn = (w & 1) * (BN / 2);

    floatx4 acc[FM][FN];
    for (int mi = 0; mi < FM; mi++)
        for (int ni = 0; ni < FN; ni++) acc[mi][ni] = (floatx4){0.f, 0.f, 0.f, 0.f};

    const int rg = lane >> 3;
    const int ce = ((lane & 7) ^ rg) * 8;
    size_t gA[GA], gB[GB];
    for (int g = 0; g < GA; g++) {
        int row = w * (BM / 4) + g * 8 + rg;
        gA[g] = (size_t)(m0 + row) * K + ce;
    }
    for (int g = 0; g < GB; g++) {
        int row = w * (BN / 4) + g * 8 + rg;
        gB[g] = (size_t)(n0 + row) * K + ce;
    }

    for (int k0 = 0; k0 < K; k0 += 64) {
        for (int g = 0; g < GA; g++)
            gld16(A + gA[g] + k0, &lA[(w * (BM / 4) + g * 8) * 64]);
        for (int g = 0; g < GB; g++)
            gld16(B + gB[g] + k0, &lB[(w * (BN / 4) + g * 8) * 64]);
        __syncthreads();
        short8 af[FM][2], bf[FN][2];
        for (int mi = 0; mi < FM; mi++) {
            int row = wm + mi * 16 + qi;
            for (int kh = 0; kh < 2; kh++)
                af[mi][kh] = *(const short8*)&lA[row * 64 + (((kh * 4 + quad) ^ (row & 7)) << 3)];
        }
        for (int ni = 0; ni < FN; ni++) {
            int row = wn + ni * 16 + qi;
            for (int kh = 0; kh < 2; kh++)
                bf[ni][kh] = *(const short8*)&lB[row * 64 + (((kh * 4 + quad) ^ (row & 7)) << 3)];
        }
        for (int mi = 0; mi < FM; mi++)
            for (int ni = 0; ni < FN; ni++) {
                acc[mi][ni] = __builtin_amdgcn_mfma_f32_16x16x32_bf16(af[mi][0], bf[ni][0], acc[mi][ni], 0, 0, 0);
                acc[mi][ni] = __builtin_amdgcn_mfma_f32_16x16x32_bf16(af[mi][1], bf[ni][1], acc[mi][ni], 0, 0, 0);
            }
        __syncthreads();
    }
    for (int mi = 0; mi < FM; mi++)
        for (int ni = 0; ni < FN; ni++) {
            int col = n0 + wn + ni * 16 + qi;
            int rowb = m0 + wm + mi * 16 + quad * 4;
            float b = bias[col];
            for (int r = 0; r < 4; r++)
                C[(size_t)(rowb + r) * N + col] = acc[mi][ni][r] + b;
        }
}

// ---------------- flash attention: QT=128, 4 waves x 32q (2 qg), key-split 2 ----------------
// Counted-vmcnt dual-barrier pipeline (frozen control, ~65 us floor across 5 variants).
__global__ __launch_bounds__(256, 3) void attn_k(
    const u16* __restrict__ Qs, const u16* __restrict__ Ks, const u16* __restrict__ Vs,
    float* __restrict__ Op, float* __restrict__ lp) {
    __shared__ u16 kbuf[2][5120];  // 10KB each; pair doubles as 20KB Q staging
    __shared__ u16 vbuf[2][5120];  // 10KB each

    const int t = threadIdx.x, lane = t & 63, w = t >> 6;  // w in 0..3
    const int qi = lane & 15, quad = lane >> 4;
    const int h = blockIdx.y, q0 = blockIdx.x * 128, ksp = blockIdx.z;
    const int kc0 = ksp * (SEQ / 2);
    u16* const kflat = &kbuf[0][0];

    {   // stage Q: 128 rows x 160B = 20KB across the kbuf pair
        const u16* Qt = Qs + (size_t)(h * SEQ + q0) * 80;
        for (int j = 0; j < 5; j++) {
            int o = (w * 5 + j) * 512;
            gld16(Qt + o + lane * 8, kflat + o);
        }
    }
    __syncthreads();
    short8 bq[2][3];
    for (int qg = 0; qg < 2; qg++) {
        const u16* rb = &kflat[(w * 32 + qg * 16 + qi) * 80];
        bq[qg][0] = *(const short8*)&rb[(quad ^ (qi & 7)) << 3];
        bq[qg][1] = *(const short8*)&rb[((4 + quad) ^ (qi & 7)) << 3];
        short4v t2 = *(const short4v*)&rb[((8 + ((quad >> 1) ^ ((qi >> 2) & 1))) << 3) + ((quad & 1) << 2)];
        bq[qg][2] = (short8){t2.x, t2.y, t2.z, t2.w, 0, 0, 0, 0};
    }
    __syncthreads();   // all waves done reading Q area before stage(0) overwrites it

    float l_lane[2] = {0.f, 0.f};
    floatx4 acco[2][5];
    for (int qg = 0; qg < 2; qg++)
        for (int dt = 0; dt < 5; dt++) acco[qg][dt] = (floatx4){0.f, 0.f, 0.f, 0.f};

    const u16* const Kt = Ks + (size_t)(h * SEQ + kc0) * 80;
    const u16* const Vt = Vs + (size_t)h * HD * SEQ + kc0;
    // uniform staging: 20 16B-chunk groups (10 K + 10 V), exactly 5 gld16 per wave
    auto stage = [&](int it, int buf) {
        const u16* Kti = Kt + it * (64 * 80);
        const u16* Vti = Vt + it * 64;
        for (int c = 0; c < 5; c++) {
            int j = w * 5 + c;
            if (j < 10) {
                gld16(Kti + j * 512 + lane * 8, &kbuf[buf][j * 512]);
            } else {
                int i = j - 10;
                int p16 = i * 64 + lane;
                int d = p16 >> 3, pc = p16 & 7;
                gld16(Vti + (size_t)d * SEQ + pc * 8, &vbuf[buf][i * 512]);
            }
        }
    };
    stage(0, 0);

    const int NT = (SEQ / 2) / 64;  // 24
    for (int it = 0; it < NT; it++) {
        int cur = it & 1;
        if (it + 1 < NT) {
            stage(it + 1, cur ^ 1);
            // wait only for stage(it): the 5 newest (stage(it+1)) stay in flight
            asm volatile("s_waitcnt vmcnt(5)" ::: "memory");
        } else {
            asm volatile("s_waitcnt vmcnt(0)" ::: "memory");
        }
        __builtin_amdgcn_s_barrier();
        __builtin_amdgcn_sched_barrier(0);
        const u16* kb = &kbuf[cur][0];
        const u16* vb = &vbuf[cur][0];
#pragma unroll
        for (int c2 = 0; c2 < 2; c2++) {
            u32 pkx[2][2], pky[2][2];  // [qg][ktl]
#pragma unroll
            for (int ktl = 0; ktl < 2; ktl++) {
                int arow = (c2 * 2 + ktl) * 16 + qi;
                const u16* rb = &kb[arow * 80];
                short8 a0 = *(const short8*)&rb[(quad ^ (qi & 7)) << 3];
                short8 a1 = *(const short8*)&rb[((4 + quad) ^ (qi & 7)) << 3];
                short4v a2v = *(const short4v*)&rb[((8 + ((quad >> 1) ^ ((qi >> 2) & 1))) << 3) + ((quad & 1) << 2)];
                short8 a2 = (short8){a2v.x, a2v.y, a2v.z, a2v.w, 0, 0, 0, 0};
#pragma unroll
                for (int qg = 0; qg < 2; qg++) {
                    floatx4 s = (floatx4){0.f, 0.f, 0.f, 0.f};
                    __builtin_amdgcn_s_setprio(1);
                    s = __builtin_amdgcn_mfma_f32_16x16x32_bf16(a0, bq[qg][0], s, 0, 0, 0);
                    s = __builtin_amdgcn_mfma_f32_16x16x32_bf16(a1, bq[qg][1], s, 0, 0, 0);
                    s = __builtin_amdgcn_mfma_f32_16x16x32_bf16(a2, bq[qg][2], s, 0, 0, 0);
                    __builtin_amdgcn_s_setprio(0);
                    float e0 = __builtin_amdgcn_exp2f(s[0]);
                    float e1 = __builtin_amdgcn_exp2f(s[1]);
                    float e2 = __builtin_amdgcn_exp2f(s[2]);
                    float e3 = __builtin_amdgcn_exp2f(s[3]);
                    l_lane[qg] += (e0 + e1) + (e2 + e3);
                    pkx[qg][ktl] = __builtin_amdgcn_perm(__float_as_uint(e1), __float_as_uint(e0), 0x07060302u);
                    pky[qg][ktl] = __builtin_amdgcn_perm(__float_as_uint(e3), __float_as_uint(e2), 0x07060302u);
                }
            }
            short8 bp[2];
#pragma unroll
            for (int qg = 0; qg < 2; qg++) {
                auto s0 = __builtin_amdgcn_permlane32_swap(pkx[qg][0], pkx[qg][1], false, false);
                auto s1 = __builtin_amdgcn_permlane32_swap(pky[qg][0], pky[qg][1], false, false);
                auto t0 = __builtin_amdgcn_permlane16_swap(s0[0], s0[1], false, false);
                auto t1 = __builtin_amdgcn_permlane16_swap(s1[0], s1[1], false, false);
                uint4v bb = (uint4v){t0[0], t1[0], t0[1], t1[1]};
                bp[qg] = __builtin_bit_cast(short8, bb);
            }
            int pv = (4 * c2 + quad) ^ (qi & 7);
            __builtin_amdgcn_s_setprio(1);
#pragma unroll
            for (int dt = 0; dt < 5; dt++) {
                short8 av = *(const short8*)&vb[((dt * 16 + qi) * 8 + pv) * 8];
                acco[0][dt] = __builtin_amdgcn_mfma_f32_16x16x32_bf16(av, bp[0], acco[0][dt], 0, 0, 0);
                acco[1][dt] = __builtin_amdgcn_mfma_f32_16x16x32_bf16(av, bp[1], acco[1][dt], 0, 0, 0);
            }
            __builtin_amdgcn_s_setprio(0);
        }
        // all waves done reading buf[cur] before next iter's stage overwrites it
        __builtin_amdgcn_s_barrier();
    }

    for (int qg = 0; qg < 2; qg++) {
        float lq = l_lane[qg];
        lq += __shfl_xor(lq, 16);
        lq += __shfl_xor(lq, 32);
        int q = q0 + w * 32 + qg * 16 + qi;
        if (quad == 0) lp[(size_t)(ksp * NH + h) * SEQ + q] = lq;
        for (int dt = 0; dt < 5; dt++)
            for (int r = 0; r < 4; r++) {
                int d = dt * 16 + quad * 4 + r;
                Op[((size_t)(ksp * NH + h) * HD + d) * SEQ + q] = acco[qg][dt][r];
            }
    }
}

// ---------------- merge key-split partials -> att bf16 [SEQ][HID] ----------------
__global__ void merge_k(const float* __restrict__ Op, const float* __restrict__ lp,
                        u16* __restrict__ att) {
    __shared__ float ls[HD * 65];
    __shared__ float li[64];
    const int t = threadIdx.x;
    const int h = blockIdx.y, q0 = blockIdx.x * 64;
    for (int i = t; i < HD * 16; i += 256) {
        int d = i / 16, g = i % 16;
        size_t a0 = ((size_t)h * HD + d) * SEQ + q0 + g * 4;
        size_t a1 = ((size_t)(NH + h) * HD + d) * SEQ + q0 + g * 4;
        const float4 v0 = *(const float4*)&Op[a0];
        const float4 v1 = *(const float4*)&Op[a1];
        ls[d * 65 + g * 4 + 0] = v0.x + v1.x;
        ls[d * 65 + g * 4 + 1] = v0.y + v1.y;
        ls[d * 65 + g * 4 + 2] = v0.z + v1.z;
        ls[d * 65 + g * 4 + 3] = v0.w + v1.w;
    }
    if (t < 64)
        li[t] = 1.0f / (lp[(size_t)h * SEQ + q0 + t] + lp[(size_t)(NH + h) * SEQ + q0 + t]);
    __syncthreads();
    for (int i = t; i < 64 * 40; i += 256) {
        int ql = i / 40, dg = i % 40;
        int d0 = dg * 2;
        float s = li[ql];
        u32 o = packrne(ls[d0 * 65 + ql] * s, ls[(d0 + 1) * 65 + ql] * s);
        *(u32*)&att[(size_t)(q0 + ql) * HID + h * HD + d0] = o;
    }
}

extern "C" void kernel_launch(void* const* d_in, const int* in_sizes, int n_in,
                              void* d_out, int out_size, void* d_ws, size_t ws_size,
                              hipStream_t stream) {
    const float* hs   = (const float*)d_in[0];
    const int*   pos  = (const int*)d_in[1];
    const float* qkvw = (const float*)d_in[2];
    const float* qkvb = (const float*)d_in[3];
    const float* ow   = (const float*)d_in[4];
    const float* ob   = (const float*)d_in[5];
    float* out = (float*)d_out;

    char* p = (char*)d_ws;
    auto alloc = [&](size_t bytes) {
        char* r = p;
        p += (bytes + 255) & ~(size_t)255;
        return r;
    };
    float2* csb = (float2*)alloc((size_t)SEQ * 40 * 8);          // rope (cos,sin) table
    u16* owT = (u16*)alloc((size_t)HID * HID * 2);
    u16* hH  = (u16*)alloc((size_t)SEQ * HID * 2);               // phase A; aliased by att later
    u16* Qs  = (u16*)alloc((size_t)NH * SEQ * HD * 2);
    u16* Ks  = (u16*)alloc((size_t)NH * SEQ * HD * 2);
    u16* Vs  = (u16*)alloc((size_t)NH * SEQ * HD * 2);
    // pool: phase A = qkv_w^T bf16 (9.8MB); phase B = Op f32 partials (31.5MB)
    char* poolB = alloc((size_t)KSP * NH * HD * SEQ * 4);
    u16* wT = (u16*)poolB;
    float* Op = (float*)poolB;
    float* lp = (float*)alloc((size_t)KSP * NH * SEQ * 4);
    u16* att = hH;  // alias: hH dead after qkv GEMM; att born in merge

    hipLaunchKernelGGL(prep_k, dim3(10720), dim3(256), 0, stream,
                       pos, csb, hs, hH, qkvw, wT, ow, owT);
    hipLaunchKernelGGL(gemm_qkv_k, dim3(768), dim3(256), 0, stream,
                       hH, wT, qkvb, csb, Qs, Ks, Vs);
    hipLaunchKernelGGL(attn_k, dim3(SEQ / 128, NH, 2), dim3(256), 0, stream,
                       Qs, Ks, Vs, Op, lp);
    hipLaunchKernelGGL(merge_k, dim3(SEQ / 64, NH), dim3(256), 0, stream, Op, lp, att);
    hipLaunchKernelGGL((gemm_bf16_k<64, 64>), dim3(960), dim3(256), 0, stream,
                       att, owT, ob, out, SEQ, HID, HID, 1);
}